// Round 1
// baseline (2606.045 us; speedup 1.0000x reference)
//
#include <hip/hip_runtime.h>
#include <math.h>

// ---------------------------------------------------------------------------
// SiReN loss on MI355X.
// Pipeline: deg -> dinv -> prop(E->b1) -> prop(b1->b2) -> mlp(E2->zn)
//           -> fuse(z_p,z_n -> Z, stored over b1) -> score -> scalar loss.
// Workspace layout (floats): [dinv NN][b1 NN*64][b2 NN*64][zn NN*64]
// ---------------------------------------------------------------------------

__global__ void k_deg(const int* __restrict__ dst, float* __restrict__ deg, int NE) {
  int e = blockIdx.x * blockDim.x + threadIdx.x;
  if (e < NE) unsafeAtomicAdd(&deg[dst[e]], 1.0f);
}

__global__ void k_dinv(float* __restrict__ deg, int NN) {
  int i = blockIdx.x * blockDim.x + threadIdx.x;
  if (i < NN) {
    float d = deg[i];
    deg[i] = (d > 0.f) ? rsqrtf(d) : 0.f;
  }
}

// one wave per edge, lane = dim
__global__ void k_prop(const float* __restrict__ x, const int* __restrict__ src,
                       const int* __restrict__ dst, const float* __restrict__ dinv,
                       float* __restrict__ out, int NE) {
  int gid = blockIdx.x * blockDim.x + threadIdx.x;
  int e = gid >> 6;
  if (e >= NE) return;
  int lane = gid & 63;
  int s = src[e], t = dst[e];
  float nrm = dinv[s] * dinv[t];
  unsafeAtomicAdd(&out[t * 64 + lane], x[s * 64 + lane] * nrm);
}

// wave per node: zn = relu(relu(E2 @ W0^T + b0) @ W1^T + b1)
__global__ __launch_bounds__(256) void k_mlp(const float* __restrict__ E2,
                                             const float* __restrict__ Wm,
                                             const float* __restrict__ bm,
                                             float* __restrict__ zn, int NN) {
  __shared__ float W0t[64 * 65];
  __shared__ float W1t[64 * 65];
  __shared__ float b0s[64];
  __shared__ float b1s[64];
  int t = threadIdx.x;
  for (int idx = t; idx < 4096; idx += 256) {
    int j = idx >> 6, d = idx & 63;
    W0t[d * 65 + j] = Wm[idx];
    W1t[d * 65 + j] = Wm[4096 + idx];
  }
  if (t < 64) { b0s[t] = bm[t]; b1s[t] = bm[64 + t]; }
  __syncthreads();
  int node = blockIdx.x * 4 + (t >> 6);
  if (node >= NN) return;
  int j = t & 63;
  float e2 = E2[node * 64 + j];
  float acc = b0s[j];
#pragma unroll
  for (int d = 0; d < 64; ++d) acc += __shfl(e2, d) * W0t[d * 65 + j];
  float h = fmaxf(acc, 0.f);
  float acc2 = b1s[j];
#pragma unroll
  for (int d = 0; d < 64; ++d) acc2 += __shfl(h, d) * W1t[d * 65 + j];
  zn[node * 64 + j] = fmaxf(acc2, 0.f);
}

// wave per node: attention fusion; writes Z over b1
__global__ __launch_bounds__(256) void k_fuse(const float* __restrict__ E,
                                              float* __restrict__ b1buf,
                                              const float* __restrict__ b2buf,
                                              const float* __restrict__ zn,
                                              const float* __restrict__ AW,
                                              const float* __restrict__ ab,
                                              const float* __restrict__ qw, int NN) {
  __shared__ float AWt[64 * 65];
  __shared__ float abs_[64];
  __shared__ float qs[64];
  int t = threadIdx.x;
  for (int idx = t; idx < 4096; idx += 256) {
    int j = idx >> 6, d = idx & 63;
    AWt[d * 65 + j] = AW[idx];
  }
  if (t < 64) { abs_[t] = ab[t]; qs[t] = qw[t]; }
  __syncthreads();
  int node = blockIdx.x * 4 + (t >> 6);
  if (node >= NN) return;
  int j = t & 63;
  long base = (long)node * 64 + j;
  float zp = (E[base] + b1buf[base] + b2buf[base]) * (1.f / 3.f);
  float zv = zn[base];
  float a1acc = abs_[j], a2acc = abs_[j];
#pragma unroll
  for (int d = 0; d < 64; ++d) {
    float wcol = AWt[d * 65 + j];
    a1acc += __shfl(zp, d) * wcol;
    a2acc += __shfl(zv, d) * wcol;
  }
  float t1 = tanhf(a1acc) * qs[j];
  float t2 = tanhf(a2acc) * qs[j];
#pragma unroll
  for (int off = 32; off; off >>= 1) {
    t1 += __shfl_xor(t1, off);
    t2 += __shfl_xor(t2, off);
  }
  float m = fmaxf(t1, t2);
  float e1 = expf(t1 - m), e2 = expf(t2 - m);
  float inv = 1.f / (e1 + e2);
  float a0 = e1 * inv, a1 = e2 * inv;
  b1buf[base] = a0 * zp + a1 * zv;
}

// 256 blocks, wave per batch element (grid-stride), block partial -> atomic
__global__ __launch_bounds__(256) void k_score(const float* __restrict__ Z,
                                               const int* __restrict__ u,
                                               const int* __restrict__ v,
                                               const int* __restrict__ n,
                                               const float* __restrict__ w,
                                               float* __restrict__ out, int B, int K) {
  __shared__ float part[4];
  int t = threadIdx.x;
  int lane = t & 63, wv = t >> 6;
  float wacc = 0.f;
  for (int b = blockIdx.x * 4 + wv; b < B; b += gridDim.x * 4) {
    int uid = u[b], vid = v[b];
    float uval = Z[(long)uid * 64 + lane];
    float vval = Z[(long)vid * 64 + lane];
    float p = uval * vval;
#pragma unroll
    for (int off = 32; off; off >>= 1) p += __shfl_xor(p, off);
    float wb = w[b];
    float sgn = (wb > 0.f) ? 1.f : ((wb < 0.f) ? -1.f : 0.f);
    float sp = sgn * p;
    float reg = uval * uval + vval * vval;
    float sb = 0.f;
    for (int k = 0; k < K; ++k) {
      int nid = n[b * K + k];
      float nv = Z[(long)nid * 64 + lane];
      float dotv = uval * nv;
#pragma unroll
      for (int off = 32; off; off >>= 1) dotv += __shfl_xor(dotv, off);
      reg += nv * nv;
      float x = sp - dotv;
      sb += fminf(x, 0.f) - log1pf(expf(-fabsf(x)));
    }
#pragma unroll
    for (int off = 32; off; off >>= 1) reg += __shfl_xor(reg, off);
    wacc += -sb + 1e-4f * reg;
  }
  if (lane == 0) part[wv] = wacc;
  __syncthreads();
  if (t == 0) {
    unsafeAtomicAdd(out, part[0] + part[1] + part[2] + part[3]);
  }
}

extern "C" void kernel_launch(void* const* d_in, const int* in_sizes, int n_in,
                              void* d_out, int out_size, void* d_ws, size_t ws_size,
                              hipStream_t stream) {
  const float* E  = (const float*)d_in[0];
  const float* E2 = (const float*)d_in[1];
  const float* Wm = (const float*)d_in[2];
  const float* bm = (const float*)d_in[3];
  const float* AW = (const float*)d_in[4];
  const float* ab = (const float*)d_in[5];
  const float* qw = (const float*)d_in[6];
  const int*   ei = (const int*)d_in[7];
  const int*   u  = (const int*)d_in[8];
  const int*   v  = (const int*)d_in[9];
  const int*   nn = (const int*)d_in[10];
  const float* w  = (const float*)d_in[11];

  const int NN = in_sizes[0] / 64;        // 150000
  const int NE = in_sizes[7] / 2;         // 3200000
  const int B  = in_sizes[8];             // 16384
  const int K  = in_sizes[10] / B;        // 40

  const int* src = ei;
  const int* dst = ei + NE;

  float* ws   = (float*)d_ws;
  float* dinv = ws;                       // NN
  float* b1   = dinv + NN;                // NN*64
  float* b2   = b1 + (size_t)NN * 64;     // NN*64
  float* zn   = b2 + (size_t)NN * 64;     // NN*64
  float* outf = (float*)d_out;

  // zero: dinv + b1 + b2 (contiguous), and the output scalar
  hipMemsetAsync(ws, 0, (size_t)NN * (1 + 64 + 64) * sizeof(float), stream);
  hipMemsetAsync(outf, 0, sizeof(float), stream);

  k_deg<<<(NE + 255) / 256, 256, 0, stream>>>(dst, dinv, NE);
  k_dinv<<<(NN + 255) / 256, 256, 0, stream>>>(dinv, NN);

  int propBlocks = (NE * 64 + 255) / 256;   // 64 lanes per edge
  k_prop<<<propBlocks, 256, 0, stream>>>(E, src, dst, dinv, b1, NE);
  k_prop<<<propBlocks, 256, 0, stream>>>(b1, src, dst, dinv, b2, NE);

  int nodeBlocks = (NN + 3) / 4;
  k_mlp<<<nodeBlocks, 256, 0, stream>>>(E2, Wm, bm, zn, NN);
  k_fuse<<<nodeBlocks, 256, 0, stream>>>(E, b1, b2, zn, AW, ab, qw, NN);

  k_score<<<256, 256, 0, stream>>>(b1, u, v, nn, w, outf, B, K);
}

// Round 2
// 1747.296 us; speedup vs baseline: 1.4915x; 1.4915x over previous
//
#include <hip/hip_runtime.h>
#include <math.h>

// ---------------------------------------------------------------------------
// SiReN loss on MI355X — round 2: CSR gather propagation (no float atomics).
// Pipeline: count -> scan(rowptr) -> dinv -> scatter(CSR) ->
//           gather(E->b1) -> gather(b1->b2) -> mlp -> fuse -> score.
// ---------------------------------------------------------------------------

__global__ void k_count(const int* __restrict__ dst, int* __restrict__ deg, int NE) {
  int e = blockIdx.x * blockDim.x + threadIdx.x;
  if (e < NE) atomicAdd(&deg[dst[e]], 1);
}

// phase 1: per-block sums of deg
__global__ void k_scan1(const int* __restrict__ deg, int* __restrict__ bsum, int NN) {
  __shared__ int sm[256];
  int t = threadIdx.x;
  int i = blockIdx.x * 256 + t;
  sm[t] = (i < NN) ? deg[i] : 0;
  __syncthreads();
  for (int s = 128; s > 0; s >>= 1) {
    if (t < s) sm[t] += sm[t + s];
    __syncthreads();
  }
  if (t == 0) bsum[blockIdx.x] = sm[0];
}

// phase 2: exclusive scan of block sums (nb <= 1024), single block
__global__ void k_scan2(int* __restrict__ bsum, int nb) {
  __shared__ int sm[1024];
  int t = threadIdx.x;
  int v = (t < nb) ? bsum[t] : 0;
  sm[t] = v;
  __syncthreads();
  for (int off = 1; off < 1024; off <<= 1) {
    int add = (t >= off) ? sm[t - off] : 0;
    __syncthreads();
    sm[t] += add;
    __syncthreads();
  }
  if (t < nb) bsum[t] = sm[t] - v;  // exclusive
}

// phase 3: within-block exclusive scan + block offset -> rowptr
__global__ void k_scan3(const int* __restrict__ deg, const int* __restrict__ bsum,
                        int* __restrict__ rowptr, int NN) {
  __shared__ int sm[256];
  int t = threadIdx.x;
  int i = blockIdx.x * 256 + t;
  int v = (i < NN) ? deg[i] : 0;
  sm[t] = v;
  __syncthreads();
  for (int off = 1; off < 256; off <<= 1) {
    int add = (t >= off) ? sm[t - off] : 0;
    __syncthreads();
    sm[t] += add;
    __syncthreads();
  }
  int incl = sm[t] + bsum[blockIdx.x];
  if (i < NN) rowptr[i] = incl - v;
  if (i == NN - 1) rowptr[NN] = incl;
}

__global__ void k_dinv(const int* __restrict__ deg, float* __restrict__ dinv, int NN) {
  int i = blockIdx.x * blockDim.x + threadIdx.x;
  if (i < NN) {
    int d = deg[i];
    dinv[i] = (d > 0) ? rsqrtf((float)d) : 0.f;
  }
}

__global__ void k_scatter(const int* __restrict__ src, const int* __restrict__ dst,
                          const float* __restrict__ dinv, const int* __restrict__ rowptr,
                          int* __restrict__ cursor, int* __restrict__ csrc,
                          float* __restrict__ cnorm, int NE) {
  int e = blockIdx.x * blockDim.x + threadIdx.x;
  if (e >= NE) return;
  int s = src[e], d = dst[e];
  int pos = rowptr[d] + atomicAdd(&cursor[d], 1);
  csrc[pos] = s;
  cnorm[pos] = dinv[s] * dinv[d];
}

// wave per node, lane = dim: out[node] = sum_neighbors norm * x[src]
__global__ __launch_bounds__(256) void k_gather(const float* __restrict__ x,
                                                const int* __restrict__ rowptr,
                                                const int* __restrict__ csrc,
                                                const float* __restrict__ cnorm,
                                                float* __restrict__ out, int NN) {
  int gid = blockIdx.x * blockDim.x + threadIdx.x;
  int node = gid >> 6;
  if (node >= NN) return;
  int lane = gid & 63;
  int beg = rowptr[node], end = rowptr[node + 1];
  float acc = 0.f;
  int i = beg;
  for (; i + 1 < end; i += 2) {
    int s0 = csrc[i], s1 = csrc[i + 1];
    float n0 = cnorm[i], n1 = cnorm[i + 1];
    float x0 = x[(size_t)s0 * 64 + lane];
    float x1 = x[(size_t)s1 * 64 + lane];
    acc += n0 * x0;
    acc += n1 * x1;
  }
  if (i < end) {
    acc += cnorm[i] * x[(size_t)csrc[i] * 64 + lane];
  }
  out[(size_t)node * 64 + lane] = acc;
}

// wave per node: zn = relu(relu(E2 @ W0^T + b0) @ W1^T + b1)
__global__ __launch_bounds__(256) void k_mlp(const float* __restrict__ E2,
                                             const float* __restrict__ Wm,
                                             const float* __restrict__ bm,
                                             float* __restrict__ zn, int NN) {
  __shared__ float W0t[64 * 65];
  __shared__ float W1t[64 * 65];
  __shared__ float b0s[64];
  __shared__ float b1s[64];
  int t = threadIdx.x;
  for (int idx = t; idx < 4096; idx += 256) {
    int j = idx >> 6, d = idx & 63;
    W0t[d * 65 + j] = Wm[idx];
    W1t[d * 65 + j] = Wm[4096 + idx];
  }
  if (t < 64) { b0s[t] = bm[t]; b1s[t] = bm[64 + t]; }
  __syncthreads();
  int node = blockIdx.x * 4 + (t >> 6);
  if (node >= NN) return;
  int j = t & 63;
  float e2 = E2[node * 64 + j];
  float acc = b0s[j];
#pragma unroll
  for (int d = 0; d < 64; ++d) acc += __shfl(e2, d) * W0t[d * 65 + j];
  float h = fmaxf(acc, 0.f);
  float acc2 = b1s[j];
#pragma unroll
  for (int d = 0; d < 64; ++d) acc2 += __shfl(h, d) * W1t[d * 65 + j];
  zn[node * 64 + j] = fmaxf(acc2, 0.f);
}

// wave per node: attention fusion; writes Z over b1
__global__ __launch_bounds__(256) void k_fuse(const float* __restrict__ E,
                                              float* __restrict__ b1buf,
                                              const float* __restrict__ b2buf,
                                              const float* __restrict__ zn,
                                              const float* __restrict__ AW,
                                              const float* __restrict__ ab,
                                              const float* __restrict__ qw, int NN) {
  __shared__ float AWt[64 * 65];
  __shared__ float abs_[64];
  __shared__ float qs[64];
  int t = threadIdx.x;
  for (int idx = t; idx < 4096; idx += 256) {
    int j = idx >> 6, d = idx & 63;
    AWt[d * 65 + j] = AW[idx];
  }
  if (t < 64) { abs_[t] = ab[t]; qs[t] = qw[t]; }
  __syncthreads();
  int node = blockIdx.x * 4 + (t >> 6);
  if (node >= NN) return;
  int j = t & 63;
  long base = (long)node * 64 + j;
  float zp = (E[base] + b1buf[base] + b2buf[base]) * (1.f / 3.f);
  float zv = zn[base];
  float a1acc = abs_[j], a2acc = abs_[j];
#pragma unroll
  for (int d = 0; d < 64; ++d) {
    float wcol = AWt[d * 65 + j];
    a1acc += __shfl(zp, d) * wcol;
    a2acc += __shfl(zv, d) * wcol;
  }
  float t1 = tanhf(a1acc) * qs[j];
  float t2 = tanhf(a2acc) * qs[j];
#pragma unroll
  for (int off = 32; off; off >>= 1) {
    t1 += __shfl_xor(t1, off);
    t2 += __shfl_xor(t2, off);
  }
  float m = fmaxf(t1, t2);
  float e1 = expf(t1 - m), e2 = expf(t2 - m);
  float inv = 1.f / (e1 + e2);
  float a0 = e1 * inv, a1 = e2 * inv;
  b1buf[base] = a0 * zp + a1 * zv;
}

// 256 blocks, wave per batch element (grid-stride), block partial -> atomic
__global__ __launch_bounds__(256) void k_score(const float* __restrict__ Z,
                                               const int* __restrict__ u,
                                               const int* __restrict__ v,
                                               const int* __restrict__ n,
                                               const float* __restrict__ w,
                                               float* __restrict__ out, int B, int K) {
  __shared__ float part[4];
  int t = threadIdx.x;
  int lane = t & 63, wv = t >> 6;
  float wacc = 0.f;
  for (int b = blockIdx.x * 4 + wv; b < B; b += gridDim.x * 4) {
    int uid = u[b], vid = v[b];
    float uval = Z[(long)uid * 64 + lane];
    float vval = Z[(long)vid * 64 + lane];
    float p = uval * vval;
#pragma unroll
    for (int off = 32; off; off >>= 1) p += __shfl_xor(p, off);
    float wb = w[b];
    float sgn = (wb > 0.f) ? 1.f : ((wb < 0.f) ? -1.f : 0.f);
    float sp = sgn * p;
    float reg = uval * uval + vval * vval;
    float sb = 0.f;
    for (int k = 0; k < K; ++k) {
      int nid = n[b * K + k];
      float nv = Z[(long)nid * 64 + lane];
      float dotv = uval * nv;
#pragma unroll
      for (int off = 32; off; off >>= 1) dotv += __shfl_xor(dotv, off);
      reg += nv * nv;
      float x = sp - dotv;
      sb += fminf(x, 0.f) - log1pf(expf(-fabsf(x)));
    }
#pragma unroll
    for (int off = 32; off; off >>= 1) reg += __shfl_xor(reg, off);
    wacc += -sb + 1e-4f * reg;
  }
  if (lane == 0) part[wv] = wacc;
  __syncthreads();
  if (t == 0) {
    unsafeAtomicAdd(out, part[0] + part[1] + part[2] + part[3]);
  }
}

extern "C" void kernel_launch(void* const* d_in, const int* in_sizes, int n_in,
                              void* d_out, int out_size, void* d_ws, size_t ws_size,
                              hipStream_t stream) {
  const float* E  = (const float*)d_in[0];
  const float* E2 = (const float*)d_in[1];
  const float* Wm = (const float*)d_in[2];
  const float* bm = (const float*)d_in[3];
  const float* AW = (const float*)d_in[4];
  const float* ab = (const float*)d_in[5];
  const float* qw = (const float*)d_in[6];
  const int*   ei = (const int*)d_in[7];
  const int*   u  = (const int*)d_in[8];
  const int*   v  = (const int*)d_in[9];
  const int*   nn = (const int*)d_in[10];
  const float* w  = (const float*)d_in[11];

  const int NN = in_sizes[0] / 64;        // 150000
  const int NE = in_sizes[7] / 2;         // 3200000
  const int B  = in_sizes[8];             // 16384
  const int K  = in_sizes[10] / B;        // 40

  const int* src = ei;
  const int* dst = ei + NE;

  // workspace layout
  float* ws     = (float*)d_ws;
  float* dinv   = ws;                         // NN floats
  float* b1     = dinv + NN;                  // NN*64
  float* b2     = b1 + (size_t)NN * 64;       // NN*64
  float* zn     = b2 + (size_t)NN * 64;       // NN*64
  int*   deg_i  = (int*)(zn + (size_t)NN * 64);   // NN ints
  int*   cursor = deg_i + NN;                 // NN ints
  int*   rowptr = cursor + NN;                // NN+1 ints
  int*   bsum   = rowptr + NN + 1;            // <=1024 ints
  int*   csrc   = bsum + 1024;                // NE ints
  float* cnorm  = (float*)(csrc + NE);        // NE floats
  float* outf   = (float*)d_out;

  const int nb = (NN + 255) / 256;            // scan blocks (<=1024)

  // zero: deg_i + cursor (contiguous), and the output scalar
  hipMemsetAsync(deg_i, 0, (size_t)2 * NN * sizeof(int), stream);
  hipMemsetAsync(outf, 0, sizeof(float), stream);

  k_count<<<(NE + 255) / 256, 256, 0, stream>>>(dst, deg_i, NE);
  k_scan1<<<nb, 256, 0, stream>>>(deg_i, bsum, NN);
  k_scan2<<<1, 1024, 0, stream>>>(bsum, nb);
  k_scan3<<<nb, 256, 0, stream>>>(deg_i, bsum, rowptr, NN);
  k_dinv<<<(NN + 255) / 256, 256, 0, stream>>>(deg_i, dinv, NN);
  k_scatter<<<(NE + 255) / 256, 256, 0, stream>>>(src, dst, dinv, rowptr, cursor,
                                                  csrc, cnorm, NE);

  int nodeBlocks4 = (NN * 64 + 255) / 256;    // wave per node
  k_gather<<<nodeBlocks4, 256, 0, stream>>>(E, rowptr, csrc, cnorm, b1, NN);
  k_gather<<<nodeBlocks4, 256, 0, stream>>>(b1, rowptr, csrc, cnorm, b2, NN);

  int nodeBlocks = (NN + 3) / 4;
  k_mlp<<<nodeBlocks, 256, 0, stream>>>(E2, Wm, bm, zn, NN);
  k_fuse<<<nodeBlocks, 256, 0, stream>>>(E, b1, b2, zn, AW, ab, qw, NN);

  k_score<<<256, 256, 0, stream>>>(b1, u, v, nn, w, outf, B, K);
}

// Round 3
// 1204.193 us; speedup vs baseline: 2.1641x; 1.4510x over previous
//
#include <hip/hip_runtime.h>
#include <math.h>

// ---------------------------------------------------------------------------
// SiReN loss on MI355X — round 3: 16-lane/float4 sub-group restructure of
// k_score (occupancy was 11.7%) and k_gather (vector loads, 4 nodes/wave).
// Workspace: [dinv NN][b1 NN*64][b2 NN*64][zn NN*64][deg NN][cursor NN]
//            [rowptr NN+1][bsum 1024][csrc NE][cnorm NE]
// ---------------------------------------------------------------------------

__global__ void k_count(const int* __restrict__ dst, int* __restrict__ deg, int NE) {
  int e = blockIdx.x * blockDim.x + threadIdx.x;
  if (e < NE) atomicAdd(&deg[dst[e]], 1);
}

// phase 1: per-block sums of deg
__global__ void k_scan1(const int* __restrict__ deg, int* __restrict__ bsum, int NN) {
  __shared__ int sm[256];
  int t = threadIdx.x;
  int i = blockIdx.x * 256 + t;
  sm[t] = (i < NN) ? deg[i] : 0;
  __syncthreads();
  for (int s = 128; s > 0; s >>= 1) {
    if (t < s) sm[t] += sm[t + s];
    __syncthreads();
  }
  if (t == 0) bsum[blockIdx.x] = sm[0];
}

// phase 2: exclusive scan of block sums (nb <= 1024), single block
__global__ void k_scan2(int* __restrict__ bsum, int nb) {
  __shared__ int sm[1024];
  int t = threadIdx.x;
  int v = (t < nb) ? bsum[t] : 0;
  sm[t] = v;
  __syncthreads();
  for (int off = 1; off < 1024; off <<= 1) {
    int add = (t >= off) ? sm[t - off] : 0;
    __syncthreads();
    sm[t] += add;
    __syncthreads();
  }
  if (t < nb) bsum[t] = sm[t] - v;  // exclusive
}

// phase 3: within-block exclusive scan + block offset -> rowptr
__global__ void k_scan3(const int* __restrict__ deg, const int* __restrict__ bsum,
                        int* __restrict__ rowptr, int NN) {
  __shared__ int sm[256];
  int t = threadIdx.x;
  int i = blockIdx.x * 256 + t;
  int v = (i < NN) ? deg[i] : 0;
  sm[t] = v;
  __syncthreads();
  for (int off = 1; off < 256; off <<= 1) {
    int add = (t >= off) ? sm[t - off] : 0;
    __syncthreads();
    sm[t] += add;
    __syncthreads();
  }
  int incl = sm[t] + bsum[blockIdx.x];
  if (i < NN) rowptr[i] = incl - v;
  if (i == NN - 1) rowptr[NN] = incl;
}

__global__ void k_dinv(const int* __restrict__ deg, float* __restrict__ dinv, int NN) {
  int i = blockIdx.x * blockDim.x + threadIdx.x;
  if (i < NN) {
    int d = deg[i];
    dinv[i] = (d > 0) ? rsqrtf((float)d) : 0.f;
  }
}

__global__ void k_scatter(const int* __restrict__ src, const int* __restrict__ dst,
                          const float* __restrict__ dinv, const int* __restrict__ rowptr,
                          int* __restrict__ cursor, int* __restrict__ csrc,
                          float* __restrict__ cnorm, int NE) {
  int e = blockIdx.x * blockDim.x + threadIdx.x;
  if (e >= NE) return;
  int s = src[e], d = dst[e];
  int pos = rowptr[d] + atomicAdd(&cursor[d], 1);
  csrc[pos] = s;
  cnorm[pos] = dinv[s] * dinv[d];
}

// 16-lane sub-group per node, lane = 4 dims (float4); 4 nodes per wave
__global__ __launch_bounds__(256) void k_gather(const float* __restrict__ x,
                                                const int* __restrict__ rowptr,
                                                const int* __restrict__ csrc,
                                                const float* __restrict__ cnorm,
                                                float* __restrict__ out, int NN) {
  int gid = blockIdx.x * blockDim.x + threadIdx.x;
  int node = gid >> 4;
  if (node >= NN) return;
  int sl = gid & 15;
  int beg = rowptr[node], end = rowptr[node + 1];
  float ax = 0.f, ay = 0.f, az = 0.f, aw = 0.f;
  int i = beg;
  for (; i + 1 < end; i += 2) {
    int s0 = csrc[i], s1 = csrc[i + 1];
    float n0 = cnorm[i], n1 = cnorm[i + 1];
    float4 x0 = *(const float4*)&x[(size_t)s0 * 64 + sl * 4];
    float4 x1 = *(const float4*)&x[(size_t)s1 * 64 + sl * 4];
    ax += n0 * x0.x; ay += n0 * x0.y; az += n0 * x0.z; aw += n0 * x0.w;
    ax += n1 * x1.x; ay += n1 * x1.y; az += n1 * x1.z; aw += n1 * x1.w;
  }
  if (i < end) {
    float n0 = cnorm[i];
    float4 x0 = *(const float4*)&x[(size_t)csrc[i] * 64 + sl * 4];
    ax += n0 * x0.x; ay += n0 * x0.y; az += n0 * x0.z; aw += n0 * x0.w;
  }
  float4 r; r.x = ax; r.y = ay; r.z = az; r.w = aw;
  *(float4*)&out[(size_t)node * 64 + sl * 4] = r;
}

// wave per node: zn = relu(relu(E2 @ W0^T + b0) @ W1^T + b1)
__global__ __launch_bounds__(256) void k_mlp(const float* __restrict__ E2,
                                             const float* __restrict__ Wm,
                                             const float* __restrict__ bm,
                                             float* __restrict__ zn, int NN) {
  __shared__ float W0t[64 * 65];
  __shared__ float W1t[64 * 65];
  __shared__ float b0s[64];
  __shared__ float b1s[64];
  int t = threadIdx.x;
  for (int idx = t; idx < 4096; idx += 256) {
    int j = idx >> 6, d = idx & 63;
    W0t[d * 65 + j] = Wm[idx];
    W1t[d * 65 + j] = Wm[4096 + idx];
  }
  if (t < 64) { b0s[t] = bm[t]; b1s[t] = bm[64 + t]; }
  __syncthreads();
  int node = blockIdx.x * 4 + (t >> 6);
  if (node >= NN) return;
  int j = t & 63;
  float e2 = E2[node * 64 + j];
  float acc = b0s[j];
#pragma unroll
  for (int d = 0; d < 64; ++d) acc += __shfl(e2, d) * W0t[d * 65 + j];
  float h = fmaxf(acc, 0.f);
  float acc2 = b1s[j];
#pragma unroll
  for (int d = 0; d < 64; ++d) acc2 += __shfl(h, d) * W1t[d * 65 + j];
  zn[node * 64 + j] = fmaxf(acc2, 0.f);
}

// wave per node: attention fusion; writes Z over b1
__global__ __launch_bounds__(256) void k_fuse(const float* __restrict__ E,
                                              float* __restrict__ b1buf,
                                              const float* __restrict__ b2buf,
                                              const float* __restrict__ zn,
                                              const float* __restrict__ AW,
                                              const float* __restrict__ ab,
                                              const float* __restrict__ qw, int NN) {
  __shared__ float AWt[64 * 65];
  __shared__ float abs_[64];
  __shared__ float qs[64];
  int t = threadIdx.x;
  for (int idx = t; idx < 4096; idx += 256) {
    int j = idx >> 6, d = idx & 63;
    AWt[d * 65 + j] = AW[idx];
  }
  if (t < 64) { abs_[t] = ab[t]; qs[t] = qw[t]; }
  __syncthreads();
  int node = blockIdx.x * 4 + (t >> 6);
  if (node >= NN) return;
  int j = t & 63;
  long base = (long)node * 64 + j;
  float zp = (E[base] + b1buf[base] + b2buf[base]) * (1.f / 3.f);
  float zv = zn[base];
  float a1acc = abs_[j], a2acc = abs_[j];
#pragma unroll
  for (int d = 0; d < 64; ++d) {
    float wcol = AWt[d * 65 + j];
    a1acc += __shfl(zp, d) * wcol;
    a2acc += __shfl(zv, d) * wcol;
  }
  float t1 = tanhf(a1acc) * qs[j];
  float t2 = tanhf(a2acc) * qs[j];
#pragma unroll
  for (int off = 32; off; off >>= 1) {
    t1 += __shfl_xor(t1, off);
    t2 += __shfl_xor(t2, off);
  }
  float m = fmaxf(t1, t2);
  float e1 = expf(t1 - m), e2 = expf(t2 - m);
  float inv = 1.f / (e1 + e2);
  float a0 = e1 * inv, a1 = e2 * inv;
  b1buf[base] = a0 * zp + a1 * zv;
}

// 16-lane sub-group per batch element; block handles 16; grid = ceil(B/16)
__global__ __launch_bounds__(256) void k_score(const float* __restrict__ Z,
                                               const int* __restrict__ u,
                                               const int* __restrict__ v,
                                               const int* __restrict__ n,
                                               const float* __restrict__ w,
                                               float* __restrict__ out, int B, int K) {
  __shared__ float xbuf[16][65];   // K <= 64
  __shared__ float part[16];
  int t = threadIdx.x;
  int wv = t >> 6, lane = t & 63;
  int sg = lane >> 4, sl = lane & 15;
  int bloc = wv * 4 + sg;
  int b = blockIdx.x * 16 + bloc;
  float lossb = 0.f;
  if (b < B) {
    int uid = u[b], vid = v[b];
    float4 u4 = *(const float4*)&Z[(size_t)uid * 64 + sl * 4];
    float4 v4 = *(const float4*)&Z[(size_t)vid * 64 + sl * 4];
    float p = u4.x * v4.x + u4.y * v4.y + u4.z * v4.z + u4.w * v4.w;
#pragma unroll
    for (int off = 8; off; off >>= 1) p += __shfl_xor(p, off);
    float wb = w[b];
    float sgn = (wb > 0.f) ? 1.f : ((wb < 0.f) ? -1.f : 0.f);
    float sp = sgn * p;
    float regl = u4.x * u4.x + u4.y * u4.y + u4.z * u4.z + u4.w * u4.w
               + v4.x * v4.x + v4.y * v4.y + v4.z * v4.z + v4.w * v4.w;
    const int* nb_ = n + (size_t)b * K;
    for (int k = 0; k < K; ++k) {
      int nid = nb_[k];
      float4 n4 = *(const float4*)&Z[(size_t)nid * 64 + sl * 4];
      float d = u4.x * n4.x + u4.y * n4.y + u4.z * n4.z + u4.w * n4.w;
      regl += n4.x * n4.x + n4.y * n4.y + n4.z * n4.z + n4.w * n4.w;
#pragma unroll
      for (int off = 8; off; off >>= 1) d += __shfl_xor(d, off);
      if (sl == 0) xbuf[bloc][k] = sp - d;
    }
#pragma unroll
    for (int off = 8; off; off >>= 1) regl += __shfl_xor(regl, off);
    // parallel log-sigmoid over the 16 lanes (same-wave LDS, no barrier needed)
    float sb = 0.f;
    for (int k = sl; k < K; k += 16) {
      float x = xbuf[bloc][k];
      sb += fminf(x, 0.f) - log1pf(expf(-fabsf(x)));
    }
#pragma unroll
    for (int off = 8; off; off >>= 1) sb += __shfl_xor(sb, off);
    lossb = -sb + 1e-4f * regl;
  }
  if (sl == 0) part[bloc] = (b < B) ? lossb : 0.f;
  __syncthreads();
  if (t == 0) {
    float s = 0.f;
#pragma unroll
    for (int i = 0; i < 16; ++i) s += part[i];
    unsafeAtomicAdd(out, s);
  }
}

extern "C" void kernel_launch(void* const* d_in, const int* in_sizes, int n_in,
                              void* d_out, int out_size, void* d_ws, size_t ws_size,
                              hipStream_t stream) {
  const float* E  = (const float*)d_in[0];
  const float* E2 = (const float*)d_in[1];
  const float* Wm = (const float*)d_in[2];
  const float* bm = (const float*)d_in[3];
  const float* AW = (const float*)d_in[4];
  const float* ab = (const float*)d_in[5];
  const float* qw = (const float*)d_in[6];
  const int*   ei = (const int*)d_in[7];
  const int*   u  = (const int*)d_in[8];
  const int*   v  = (const int*)d_in[9];
  const int*   nn = (const int*)d_in[10];
  const float* w  = (const float*)d_in[11];

  const int NN = in_sizes[0] / 64;        // 150000
  const int NE = in_sizes[7] / 2;         // 3200000
  const int B  = in_sizes[8];             // 16384
  const int K  = in_sizes[10] / B;        // 40

  const int* src = ei;
  const int* dst = ei + NE;

  // workspace layout
  float* ws     = (float*)d_ws;
  float* dinv   = ws;                         // NN floats
  float* b1     = dinv + NN;                  // NN*64
  float* b2     = b1 + (size_t)NN * 64;       // NN*64
  float* zn     = b2 + (size_t)NN * 64;       // NN*64
  int*   deg_i  = (int*)(zn + (size_t)NN * 64);   // NN ints
  int*   cursor = deg_i + NN;                 // NN ints
  int*   rowptr = cursor + NN;                // NN+1 ints
  int*   bsum   = rowptr + NN + 1;            // <=1024 ints
  int*   csrc   = bsum + 1024;                // NE ints
  float* cnorm  = (float*)(csrc + NE);        // NE floats
  float* outf   = (float*)d_out;

  const int nb = (NN + 255) / 256;            // scan blocks (<=1024)

  // zero: deg_i + cursor (contiguous), and the output scalar
  hipMemsetAsync(deg_i, 0, (size_t)2 * NN * sizeof(int), stream);
  hipMemsetAsync(outf, 0, sizeof(float), stream);

  k_count<<<(NE + 255) / 256, 256, 0, stream>>>(dst, deg_i, NE);
  k_scan1<<<nb, 256, 0, stream>>>(deg_i, bsum, NN);
  k_scan2<<<1, 1024, 0, stream>>>(bsum, nb);
  k_scan3<<<nb, 256, 0, stream>>>(deg_i, bsum, rowptr, NN);
  k_dinv<<<(NN + 255) / 256, 256, 0, stream>>>(deg_i, dinv, NN);
  k_scatter<<<(NE + 255) / 256, 256, 0, stream>>>(src, dst, dinv, rowptr, cursor,
                                                  csrc, cnorm, NE);

  int gatherBlocks = ((size_t)NN * 16 + 255) / 256;   // 16 lanes per node
  k_gather<<<gatherBlocks, 256, 0, stream>>>(E, rowptr, csrc, cnorm, b1, NN);
  k_gather<<<gatherBlocks, 256, 0, stream>>>(b1, rowptr, csrc, cnorm, b2, NN);

  int nodeBlocks = (NN + 3) / 4;
  k_mlp<<<nodeBlocks, 256, 0, stream>>>(E2, Wm, bm, zn, NN);
  k_fuse<<<nodeBlocks, 256, 0, stream>>>(E, b1, b2, zn, AW, ab, qw, NN);

  k_score<<<(B + 15) / 16, 256, 0, stream>>>(b1, u, v, nn, w, outf, B, K);
}

// Round 4
// 1129.679 us; speedup vs baseline: 2.3069x; 1.0660x over previous
//
#include <hip/hip_runtime.h>
#include <math.h>

// ---------------------------------------------------------------------------
// SiReN loss on MI355X — round 4: fuse MLP + attention-fusion into one
// persistent-block kernel (k_node) staging all weights in LDS ONCE per block.
// Pipeline: count -> scan -> dinv -> scatter(CSR) -> gather x2 -> k_node -> score.
// Workspace: [dinv NN][b1 NN*64][b2 NN*64][deg NN][cursor NN][rowptr NN+1]
//            [bsum 1024][csrc NE][cnorm NE]
// ---------------------------------------------------------------------------

__global__ void k_count(const int* __restrict__ dst, int* __restrict__ deg, int NE) {
  int e = blockIdx.x * blockDim.x + threadIdx.x;
  if (e < NE) atomicAdd(&deg[dst[e]], 1);
}

// phase 1: per-block sums of deg
__global__ void k_scan1(const int* __restrict__ deg, int* __restrict__ bsum, int NN) {
  __shared__ int sm[256];
  int t = threadIdx.x;
  int i = blockIdx.x * 256 + t;
  sm[t] = (i < NN) ? deg[i] : 0;
  __syncthreads();
  for (int s = 128; s > 0; s >>= 1) {
    if (t < s) sm[t] += sm[t + s];
    __syncthreads();
  }
  if (t == 0) bsum[blockIdx.x] = sm[0];
}

// phase 2: exclusive scan of block sums (nb <= 1024), single block
__global__ void k_scan2(int* __restrict__ bsum, int nb) {
  __shared__ int sm[1024];
  int t = threadIdx.x;
  int v = (t < nb) ? bsum[t] : 0;
  sm[t] = v;
  __syncthreads();
  for (int off = 1; off < 1024; off <<= 1) {
    int add = (t >= off) ? sm[t - off] : 0;
    __syncthreads();
    sm[t] += add;
    __syncthreads();
  }
  if (t < nb) bsum[t] = sm[t] - v;  // exclusive
}

// phase 3: within-block exclusive scan + block offset -> rowptr
__global__ void k_scan3(const int* __restrict__ deg, const int* __restrict__ bsum,
                        int* __restrict__ rowptr, int NN) {
  __shared__ int sm[256];
  int t = threadIdx.x;
  int i = blockIdx.x * 256 + t;
  int v = (i < NN) ? deg[i] : 0;
  sm[t] = v;
  __syncthreads();
  for (int off = 1; off < 256; off <<= 1) {
    int add = (t >= off) ? sm[t - off] : 0;
    __syncthreads();
    sm[t] += add;
    __syncthreads();
  }
  int incl = sm[t] + bsum[blockIdx.x];
  if (i < NN) rowptr[i] = incl - v;
  if (i == NN - 1) rowptr[NN] = incl;
}

__global__ void k_dinv(const int* __restrict__ deg, float* __restrict__ dinv, int NN) {
  int i = blockIdx.x * blockDim.x + threadIdx.x;
  if (i < NN) {
    int d = deg[i];
    dinv[i] = (d > 0) ? rsqrtf((float)d) : 0.f;
  }
}

__global__ void k_scatter(const int* __restrict__ src, const int* __restrict__ dst,
                          const float* __restrict__ dinv, const int* __restrict__ rowptr,
                          int* __restrict__ cursor, int* __restrict__ csrc,
                          float* __restrict__ cnorm, int NE) {
  int e = blockIdx.x * blockDim.x + threadIdx.x;
  if (e >= NE) return;
  int s = src[e], d = dst[e];
  int pos = rowptr[d] + atomicAdd(&cursor[d], 1);
  csrc[pos] = s;
  cnorm[pos] = dinv[s] * dinv[d];
}

// 16-lane sub-group per node, lane = 4 dims (float4); 4 nodes per wave
__global__ __launch_bounds__(256) void k_gather(const float* __restrict__ x,
                                                const int* __restrict__ rowptr,
                                                const int* __restrict__ csrc,
                                                const float* __restrict__ cnorm,
                                                float* __restrict__ out, int NN) {
  int gid = blockIdx.x * blockDim.x + threadIdx.x;
  int node = gid >> 4;
  if (node >= NN) return;
  int sl = gid & 15;
  int beg = rowptr[node], end = rowptr[node + 1];
  float ax = 0.f, ay = 0.f, az = 0.f, aw = 0.f;
  int i = beg;
  for (; i + 1 < end; i += 2) {
    int s0 = csrc[i], s1 = csrc[i + 1];
    float n0 = cnorm[i], n1 = cnorm[i + 1];
    float4 x0 = *(const float4*)&x[(size_t)s0 * 64 + sl * 4];
    float4 x1 = *(const float4*)&x[(size_t)s1 * 64 + sl * 4];
    ax += n0 * x0.x; ay += n0 * x0.y; az += n0 * x0.z; aw += n0 * x0.w;
    ax += n1 * x1.x; ay += n1 * x1.y; az += n1 * x1.z; aw += n1 * x1.w;
  }
  if (i < end) {
    float n0 = cnorm[i];
    float4 x0 = *(const float4*)&x[(size_t)csrc[i] * 64 + sl * 4];
    ax += n0 * x0.x; ay += n0 * x0.y; az += n0 * x0.z; aw += n0 * x0.w;
  }
  float4 r; r.x = ax; r.y = ay; r.z = az; r.w = aw;
  *(float4*)&out[(size_t)node * 64 + sl * 4] = r;
}

// ---------------------------------------------------------------------------
// Fused per-node kernel: zn = MLP(E2), zp = (E+b1+b2)/3, attention softmax,
// Z = a0*zp + a1*zn, written over b1. Weights staged in LDS ONCE per block;
// grid-stride over node groups (4 nodes per 256-thread block iteration).
// ---------------------------------------------------------------------------
__global__ __launch_bounds__(256) void k_node(const float* __restrict__ E,
                                              const float* __restrict__ E2,
                                              const float* __restrict__ Wm,
                                              const float* __restrict__ bm,
                                              const float* __restrict__ AW,
                                              const float* __restrict__ ab,
                                              const float* __restrict__ qw,
                                              float* __restrict__ b1buf,
                                              const float* __restrict__ b2buf,
                                              int NN, int ngroups) {
  __shared__ float W0t[64 * 65];
  __shared__ float W1t[64 * 65];
  __shared__ float AWt[64 * 65];
  __shared__ float b0s[64], b1s[64], abs_[64], qs[64];
  int t = threadIdx.x;
  for (int idx = t; idx < 4096; idx += 256) {
    int j = idx >> 6, d = idx & 63;
    W0t[d * 65 + j] = Wm[idx];
    W1t[d * 65 + j] = Wm[4096 + idx];
    AWt[d * 65 + j] = AW[idx];
  }
  if (t < 64) { b0s[t] = bm[t]; b1s[t] = bm[64 + t]; abs_[t] = ab[t]; qs[t] = qw[t]; }
  __syncthreads();

  int j = t & 63;
  int wv = t >> 6;
  for (int g = blockIdx.x; g < ngroups; g += gridDim.x) {
    int node = g * 4 + wv;
    if (node >= NN) continue;
    size_t base = (size_t)node * 64 + j;
    // MLP branch (z_n), fully in-register
    float e2 = E2[base];
    float acc = b0s[j];
#pragma unroll
    for (int d = 0; d < 64; ++d) acc += __shfl(e2, d) * W0t[d * 65 + j];
    float h = fmaxf(acc, 0.f);
    float acc2 = b1s[j];
#pragma unroll
    for (int d = 0; d < 64; ++d) acc2 += __shfl(h, d) * W1t[d * 65 + j];
    float zv = fmaxf(acc2, 0.f);
    // GNN branch (z_p)
    float zp = (E[base] + b1buf[base] + b2buf[base]) * (1.f / 3.f);
    // attention
    float a1acc = abs_[j], a2acc = abs_[j];
#pragma unroll
    for (int d = 0; d < 64; ++d) {
      float wcol = AWt[d * 65 + j];
      a1acc += __shfl(zp, d) * wcol;
      a2acc += __shfl(zv, d) * wcol;
    }
    float t1 = tanhf(a1acc) * qs[j];
    float t2 = tanhf(a2acc) * qs[j];
#pragma unroll
    for (int off = 32; off; off >>= 1) {
      t1 += __shfl_xor(t1, off);
      t2 += __shfl_xor(t2, off);
    }
    float m = fmaxf(t1, t2);
    float e1 = expf(t1 - m), e2e = expf(t2 - m);
    float inv = 1.f / (e1 + e2e);
    b1buf[base] = (e1 * inv) * zp + (e2e * inv) * zv;
  }
}

// 16-lane sub-group per batch element; block handles 16; grid = ceil(B/16)
__global__ __launch_bounds__(256) void k_score(const float* __restrict__ Z,
                                               const int* __restrict__ u,
                                               const int* __restrict__ v,
                                               const int* __restrict__ n,
                                               const float* __restrict__ w,
                                               float* __restrict__ out, int B, int K) {
  __shared__ float xbuf[16][65];   // K <= 64
  __shared__ float part[16];
  int t = threadIdx.x;
  int wv = t >> 6, lane = t & 63;
  int sg = lane >> 4, sl = lane & 15;
  int bloc = wv * 4 + sg;
  int b = blockIdx.x * 16 + bloc;
  float lossb = 0.f;
  if (b < B) {
    int uid = u[b], vid = v[b];
    float4 u4 = *(const float4*)&Z[(size_t)uid * 64 + sl * 4];
    float4 v4 = *(const float4*)&Z[(size_t)vid * 64 + sl * 4];
    float p = u4.x * v4.x + u4.y * v4.y + u4.z * v4.z + u4.w * v4.w;
#pragma unroll
    for (int off = 8; off; off >>= 1) p += __shfl_xor(p, off);
    float wb = w[b];
    float sgn = (wb > 0.f) ? 1.f : ((wb < 0.f) ? -1.f : 0.f);
    float sp = sgn * p;
    float regl = u4.x * u4.x + u4.y * u4.y + u4.z * u4.z + u4.w * u4.w
               + v4.x * v4.x + v4.y * v4.y + v4.z * v4.z + v4.w * v4.w;
    const int* nb_ = n + (size_t)b * K;
    for (int k = 0; k < K; ++k) {
      int nid = nb_[k];
      float4 n4 = *(const float4*)&Z[(size_t)nid * 64 + sl * 4];
      float d = u4.x * n4.x + u4.y * n4.y + u4.z * n4.z + u4.w * n4.w;
      regl += n4.x * n4.x + n4.y * n4.y + n4.z * n4.z + n4.w * n4.w;
#pragma unroll
      for (int off = 8; off; off >>= 1) d += __shfl_xor(d, off);
      if (sl == 0) xbuf[bloc][k] = sp - d;
    }
#pragma unroll
    for (int off = 8; off; off >>= 1) regl += __shfl_xor(regl, off);
    float sb = 0.f;
    for (int k = sl; k < K; k += 16) {
      float x = xbuf[bloc][k];
      sb += fminf(x, 0.f) - log1pf(expf(-fabsf(x)));
    }
#pragma unroll
    for (int off = 8; off; off >>= 1) sb += __shfl_xor(sb, off);
    lossb = -sb + 1e-4f * regl;
  }
  if (sl == 0) part[bloc] = (b < B) ? lossb : 0.f;
  __syncthreads();
  if (t == 0) {
    float s = 0.f;
#pragma unroll
    for (int i = 0; i < 16; ++i) s += part[i];
    unsafeAtomicAdd(out, s);
  }
}

extern "C" void kernel_launch(void* const* d_in, const int* in_sizes, int n_in,
                              void* d_out, int out_size, void* d_ws, size_t ws_size,
                              hipStream_t stream) {
  const float* E  = (const float*)d_in[0];
  const float* E2 = (const float*)d_in[1];
  const float* Wm = (const float*)d_in[2];
  const float* bm = (const float*)d_in[3];
  const float* AW = (const float*)d_in[4];
  const float* ab = (const float*)d_in[5];
  const float* qw = (const float*)d_in[6];
  const int*   ei = (const int*)d_in[7];
  const int*   u  = (const int*)d_in[8];
  const int*   v  = (const int*)d_in[9];
  const int*   nn = (const int*)d_in[10];
  const float* w  = (const float*)d_in[11];

  const int NN = in_sizes[0] / 64;        // 150000
  const int NE = in_sizes[7] / 2;         // 3200000
  const int B  = in_sizes[8];             // 16384
  const int K  = in_sizes[10] / B;        // 40

  const int* src = ei;
  const int* dst = ei + NE;

  // workspace layout
  float* ws     = (float*)d_ws;
  float* dinv   = ws;                         // NN floats
  float* b1     = dinv + NN;                  // NN*64
  float* b2     = b1 + (size_t)NN * 64;       // NN*64
  int*   deg_i  = (int*)(b2 + (size_t)NN * 64);   // NN ints
  int*   cursor = deg_i + NN;                 // NN ints
  int*   rowptr = cursor + NN;                // NN+1 ints
  int*   bsum   = rowptr + NN + 1;            // <=1024 ints
  int*   csrc   = bsum + 1024;                // NE ints
  float* cnorm  = (float*)(csrc + NE);        // NE floats
  float* outf   = (float*)d_out;

  const int nb = (NN + 255) / 256;            // scan blocks (<=1024)

  hipMemsetAsync(deg_i, 0, (size_t)2 * NN * sizeof(int), stream);
  hipMemsetAsync(outf, 0, sizeof(float), stream);

  k_count<<<(NE + 255) / 256, 256, 0, stream>>>(dst, deg_i, NE);
  k_scan1<<<nb, 256, 0, stream>>>(deg_i, bsum, NN);
  k_scan2<<<1, 1024, 0, stream>>>(bsum, nb);
  k_scan3<<<nb, 256, 0, stream>>>(deg_i, bsum, rowptr, NN);
  k_dinv<<<(NN + 255) / 256, 256, 0, stream>>>(deg_i, dinv, NN);
  k_scatter<<<(NE + 255) / 256, 256, 0, stream>>>(src, dst, dinv, rowptr, cursor,
                                                  csrc, cnorm, NE);

  int gatherBlocks = ((size_t)NN * 16 + 255) / 256;   // 16 lanes per node
  k_gather<<<gatherBlocks, 256, 0, stream>>>(E, rowptr, csrc, cnorm, b1, NN);
  k_gather<<<gatherBlocks, 256, 0, stream>>>(b1, rowptr, csrc, cnorm, b2, NN);

  int ngroups = (NN + 3) / 4;
  k_node<<<1024, 256, 0, stream>>>(E, E2, Wm, bm, AW, ab, qw, b1, b2, NN, ngroups);

  k_score<<<(B + 15) / 16, 256, 0, stream>>>(b1, u, v, nn, w, outf, B, K);
}

// Round 5
// 829.260 us; speedup vs baseline: 3.1426x; 1.3623x over previous
//
#include <hip/hip_runtime.h>
#include <math.h>

// ---------------------------------------------------------------------------
// SiReN loss on MI355X — round 5: k_node rewritten as a tiled f32 GEMM
// (64-node tiles, 4x4 register tiling, stride-66 LDS rows, no shuffles).
// Pipeline: count -> scan -> dinv -> scatter(CSR) -> gather x2 -> k_node -> score.
// ---------------------------------------------------------------------------

__global__ void k_count(const int* __restrict__ dst, int* __restrict__ deg, int NE) {
  int e = blockIdx.x * blockDim.x + threadIdx.x;
  if (e < NE) atomicAdd(&deg[dst[e]], 1);
}

__global__ void k_scan1(const int* __restrict__ deg, int* __restrict__ bsum, int NN) {
  __shared__ int sm[256];
  int t = threadIdx.x;
  int i = blockIdx.x * 256 + t;
  sm[t] = (i < NN) ? deg[i] : 0;
  __syncthreads();
  for (int s = 128; s > 0; s >>= 1) {
    if (t < s) sm[t] += sm[t + s];
    __syncthreads();
  }
  if (t == 0) bsum[blockIdx.x] = sm[0];
}

__global__ void k_scan2(int* __restrict__ bsum, int nb) {
  __shared__ int sm[1024];
  int t = threadIdx.x;
  int v = (t < nb) ? bsum[t] : 0;
  sm[t] = v;
  __syncthreads();
  for (int off = 1; off < 1024; off <<= 1) {
    int add = (t >= off) ? sm[t - off] : 0;
    __syncthreads();
    sm[t] += add;
    __syncthreads();
  }
  if (t < nb) bsum[t] = sm[t] - v;  // exclusive
}

__global__ void k_scan3(const int* __restrict__ deg, const int* __restrict__ bsum,
                        int* __restrict__ rowptr, int NN) {
  __shared__ int sm[256];
  int t = threadIdx.x;
  int i = blockIdx.x * 256 + t;
  int v = (i < NN) ? deg[i] : 0;
  sm[t] = v;
  __syncthreads();
  for (int off = 1; off < 256; off <<= 1) {
    int add = (t >= off) ? sm[t - off] : 0;
    __syncthreads();
    sm[t] += add;
    __syncthreads();
  }
  int incl = sm[t] + bsum[blockIdx.x];
  if (i < NN) rowptr[i] = incl - v;
  if (i == NN - 1) rowptr[NN] = incl;
}

__global__ void k_dinv(const int* __restrict__ deg, float* __restrict__ dinv, int NN) {
  int i = blockIdx.x * blockDim.x + threadIdx.x;
  if (i < NN) {
    int d = deg[i];
    dinv[i] = (d > 0) ? rsqrtf((float)d) : 0.f;
  }
}

__global__ void k_scatter(const int* __restrict__ src, const int* __restrict__ dst,
                          const float* __restrict__ dinv, const int* __restrict__ rowptr,
                          int* __restrict__ cursor, int* __restrict__ csrc,
                          float* __restrict__ cnorm, int NE) {
  int e = blockIdx.x * blockDim.x + threadIdx.x;
  if (e >= NE) return;
  int s = src[e], d = dst[e];
  int pos = rowptr[d] + atomicAdd(&cursor[d], 1);
  csrc[pos] = s;
  cnorm[pos] = dinv[s] * dinv[d];
}

// 16-lane sub-group per node, lane = 4 dims (float4); 4 nodes per wave
__global__ __launch_bounds__(256) void k_gather(const float* __restrict__ x,
                                                const int* __restrict__ rowptr,
                                                const int* __restrict__ csrc,
                                                const float* __restrict__ cnorm,
                                                float* __restrict__ out, int NN) {
  int gid = blockIdx.x * blockDim.x + threadIdx.x;
  int node = gid >> 4;
  if (node >= NN) return;
  int sl = gid & 15;
  int beg = rowptr[node], end = rowptr[node + 1];
  float ax = 0.f, ay = 0.f, az = 0.f, aw = 0.f;
  int i = beg;
  for (; i + 1 < end; i += 2) {
    int s0 = csrc[i], s1 = csrc[i + 1];
    float n0 = cnorm[i], n1 = cnorm[i + 1];
    float4 x0 = *(const float4*)&x[(size_t)s0 * 64 + sl * 4];
    float4 x1 = *(const float4*)&x[(size_t)s1 * 64 + sl * 4];
    ax += n0 * x0.x; ay += n0 * x0.y; az += n0 * x0.z; aw += n0 * x0.w;
    ax += n1 * x1.x; ay += n1 * x1.y; az += n1 * x1.z; aw += n1 * x1.w;
  }
  if (i < end) {
    float n0 = cnorm[i];
    float4 x0 = *(const float4*)&x[(size_t)csrc[i] * 64 + sl * 4];
    ax += n0 * x0.x; ay += n0 * x0.y; az += n0 * x0.z; aw += n0 * x0.w;
  }
  float4 r; r.x = ax; r.y = ay; r.z = az; r.w = aw;
  *(float4*)&out[(size_t)node * 64 + sl * 4] = r;
}

// ---------------------------------------------------------------------------
// k_node: per 64-node tile, tiled-GEMM computation of
//   zn = relu(relu(E2@W0^T+b0)@W1^T+b1); zp = (E+b1+b2)/3
//   a1 = zp@AW^T+ab, a2 = zn@AW^T+ab; w_p = tanh(a1)@q, w_n = tanh(a2)@q
//   alpha = softmax([w_p,w_n]); Z = a0*zp + a1*zn  (over b1buf)
// Thread (ty,tx) owns nodes {ty+16a} x cols {tx+16b}. LDS rows stride 66.
// ---------------------------------------------------------------------------
#define TPAD 66

__device__ inline float fast_tanh(float x) {
  float t = __expf(fminf(fmaxf(2.f * x, -30.f), 30.f));
  return (t - 1.f) / (t + 1.f);
}

__global__ __launch_bounds__(256) void k_node(const float* __restrict__ E,
                                              const float* __restrict__ E2,
                                              const float* __restrict__ Wm,
                                              const float* __restrict__ bm,
                                              const float* __restrict__ AW,
                                              const float* __restrict__ ab,
                                              const float* __restrict__ qw,
                                              float* __restrict__ b1buf,
                                              const float* __restrict__ b2buf,
                                              int NN) {
  __shared__ float W0t[64 * TPAD];
  __shared__ float W1t[64 * TPAD];
  __shared__ float AWt[64 * TPAD];
  __shared__ float TA[64 * TPAD];   // E2 tile -> ZN tile
  __shared__ float TB[64 * TPAD];   // H tile -> ZP tile
  __shared__ float b0s[64], b1s[64], abs_[64], qs[64];
  __shared__ float red1[64][17], red2[64][17];
  __shared__ float al0[64], al1[64];

  int tid = threadIdx.x;
  int tx = tid & 15, ty = tid >> 4;
  int lrow = tid >> 2;              // 0..63 (node within tile for staging)
  int lcol = (tid & 3) * 16;        // 0,16,32,48
  int node0 = blockIdx.x * 64;
  int snode = node0 + lrow;
  bool sok = snode < NN;

  // stage weights (once per block) and E2 tile
  for (int idx = tid; idx < 4096; idx += 256) {
    int j = idx >> 6, k = idx & 63;
    W0t[j * TPAD + k] = Wm[idx];
    W1t[j * TPAD + k] = Wm[4096 + idx];
    AWt[j * TPAD + k] = AW[idx];
  }
  if (tid < 64) { b0s[tid] = bm[tid]; b1s[tid] = bm[64 + tid]; abs_[tid] = ab[tid]; qs[tid] = qw[tid]; }
  {
    const float4 z4 = make_float4(0.f, 0.f, 0.f, 0.f);
    const float* sp = E2 + (size_t)snode * 64 + lcol;
#pragma unroll
    for (int c = 0; c < 4; ++c) {
      float4 xv = sok ? *(const float4*)(sp + 4 * c) : z4;
      float2* wp = (float2*)&TA[lrow * TPAD + lcol + 4 * c];
      wp[0] = make_float2(xv.x, xv.y);
      wp[1] = make_float2(xv.z, xv.w);
    }
  }
  __syncthreads();

  // GEMM1: H = relu(E2 @ W0^T + b0)  (reads TA, writes TB)
  float acc[4][4];
#pragma unroll
  for (int a = 0; a < 4; ++a)
#pragma unroll
    for (int b = 0; b < 4; ++b) acc[a][b] = b0s[tx + 16 * b];
#pragma unroll 4
  for (int k = 0; k < 64; ++k) {
    float xv[4], wv[4];
#pragma unroll
    for (int a = 0; a < 4; ++a) xv[a] = TA[(ty + 16 * a) * TPAD + k];
#pragma unroll
    for (int b = 0; b < 4; ++b) wv[b] = W0t[(tx + 16 * b) * TPAD + k];
#pragma unroll
    for (int a = 0; a < 4; ++a)
#pragma unroll
      for (int b = 0; b < 4; ++b) acc[a][b] += xv[a] * wv[b];
  }
#pragma unroll
  for (int a = 0; a < 4; ++a)
#pragma unroll
    for (int b = 0; b < 4; ++b)
      TB[(ty + 16 * a) * TPAD + tx + 16 * b] = fmaxf(acc[a][b], 0.f);
  __syncthreads();

  // GEMM2: ZN = relu(H @ W1^T + b1)  (reads TB, writes TA)
#pragma unroll
  for (int a = 0; a < 4; ++a)
#pragma unroll
    for (int b = 0; b < 4; ++b) acc[a][b] = b1s[tx + 16 * b];
#pragma unroll 4
  for (int k = 0; k < 64; ++k) {
    float xv[4], wv[4];
#pragma unroll
    for (int a = 0; a < 4; ++a) xv[a] = TB[(ty + 16 * a) * TPAD + k];
#pragma unroll
    for (int b = 0; b < 4; ++b) wv[b] = W1t[(tx + 16 * b) * TPAD + k];
#pragma unroll
    for (int a = 0; a < 4; ++a)
#pragma unroll
      for (int b = 0; b < 4; ++b) acc[a][b] += xv[a] * wv[b];
  }
  __syncthreads();   // all TB reads done before ZP overwrites it
#pragma unroll
  for (int a = 0; a < 4; ++a)
#pragma unroll
    for (int b = 0; b < 4; ++b)
      TA[(ty + 16 * a) * TPAD + tx + 16 * b] = fmaxf(acc[a][b], 0.f);

  // stage ZP = (E + b1 + b2)/3 into TB
  {
    const float4 z4 = make_float4(0.f, 0.f, 0.f, 0.f);
    const float* pe = E + (size_t)snode * 64 + lcol;
    const float* p1 = b1buf + (size_t)snode * 64 + lcol;
    const float* p2 = b2buf + (size_t)snode * 64 + lcol;
#pragma unroll
    for (int c = 0; c < 4; ++c) {
      float4 e4 = sok ? *(const float4*)(pe + 4 * c) : z4;
      float4 a4 = sok ? *(const float4*)(p1 + 4 * c) : z4;
      float4 c4 = sok ? *(const float4*)(p2 + 4 * c) : z4;
      float2* wp = (float2*)&TB[lrow * TPAD + lcol + 4 * c];
      wp[0] = make_float2((e4.x + a4.x + c4.x) * (1.f / 3.f),
                          (e4.y + a4.y + c4.y) * (1.f / 3.f));
      wp[1] = make_float2((e4.z + a4.z + c4.z) * (1.f / 3.f),
                          (e4.w + a4.w + c4.w) * (1.f / 3.f));
    }
  }
  __syncthreads();

  // Attention GEMMs: a1 = ZP@AW^T+ab (TB), a2 = ZN@AW^T+ab (TA), fused k-loop
  float ac1[4][4], ac2[4][4];
#pragma unroll
  for (int a = 0; a < 4; ++a)
#pragma unroll
    for (int b = 0; b < 4; ++b) { ac1[a][b] = abs_[tx + 16 * b]; ac2[a][b] = ac1[a][b]; }
#pragma unroll 4
  for (int k = 0; k < 64; ++k) {
    float zp[4], zn[4], wv[4];
#pragma unroll
    for (int a = 0; a < 4; ++a) {
      zp[a] = TB[(ty + 16 * a) * TPAD + k];
      zn[a] = TA[(ty + 16 * a) * TPAD + k];
    }
#pragma unroll
    for (int b = 0; b < 4; ++b) wv[b] = AWt[(tx + 16 * b) * TPAD + k];
#pragma unroll
    for (int a = 0; a < 4; ++a)
#pragma unroll
      for (int b = 0; b < 4; ++b) {
        ac1[a][b] += zp[a] * wv[b];
        ac2[a][b] += zn[a] * wv[b];
      }
  }
  // per-node partial q-dots of tanh(a)
#pragma unroll
  for (int a = 0; a < 4; ++a) {
    float p1 = 0.f, p2 = 0.f;
#pragma unroll
    for (int b = 0; b < 4; ++b) {
      float q = qs[tx + 16 * b];
      p1 += fast_tanh(ac1[a][b]) * q;
      p2 += fast_tanh(ac2[a][b]) * q;
    }
    red1[ty + 16 * a][tx] = p1;
    red2[ty + 16 * a][tx] = p2;
  }
  __syncthreads();

  if (tid < 64) {
    float wp = 0.f, wn = 0.f;
#pragma unroll
    for (int x = 0; x < 16; ++x) { wp += red1[tid][x]; wn += red2[tid][x]; }
    float m = fmaxf(wp, wn);
    float e1 = __expf(wp - m), e2 = __expf(wn - m);
    float inv = 1.f / (e1 + e2);
    al0[tid] = e1 * inv;
    al1[tid] = e2 * inv;
  }
  __syncthreads();

  // epilogue: Z = a0*ZP + a1*ZN -> b1buf (coalesced float4 stores)
  if (sok) {
    float a0 = al0[lrow], a1v = al1[lrow];
    float* op = b1buf + (size_t)snode * 64 + lcol;
#pragma unroll
    for (int c = 0; c < 4; ++c) {
      int base = lrow * TPAD + lcol + 4 * c;
      float4 o;
      o.x = a0 * TB[base + 0] + a1v * TA[base + 0];
      o.y = a0 * TB[base + 1] + a1v * TA[base + 1];
      o.z = a0 * TB[base + 2] + a1v * TA[base + 2];
      o.w = a0 * TB[base + 3] + a1v * TA[base + 3];
      *(float4*)(op + 4 * c) = o;
    }
  }
}

// 16-lane sub-group per batch element; block handles 16; grid = ceil(B/16)
__global__ __launch_bounds__(256) void k_score(const float* __restrict__ Z,
                                               const int* __restrict__ u,
                                               const int* __restrict__ v,
                                               const int* __restrict__ n,
                                               const float* __restrict__ w,
                                               float* __restrict__ out, int B, int K) {
  __shared__ float xbuf[16][65];   // K <= 64
  __shared__ float part[16];
  int t = threadIdx.x;
  int wv = t >> 6, lane = t & 63;
  int sg = lane >> 4, sl = lane & 15;
  int bloc = wv * 4 + sg;
  int b = blockIdx.x * 16 + bloc;
  float lossb = 0.f;
  if (b < B) {
    int uid = u[b], vid = v[b];
    float4 u4 = *(const float4*)&Z[(size_t)uid * 64 + sl * 4];
    float4 v4 = *(const float4*)&Z[(size_t)vid * 64 + sl * 4];
    float p = u4.x * v4.x + u4.y * v4.y + u4.z * v4.z + u4.w * v4.w;
#pragma unroll
    for (int off = 8; off; off >>= 1) p += __shfl_xor(p, off);
    float wb = w[b];
    float sgn = (wb > 0.f) ? 1.f : ((wb < 0.f) ? -1.f : 0.f);
    float sp = sgn * p;
    float regl = u4.x * u4.x + u4.y * u4.y + u4.z * u4.z + u4.w * u4.w
               + v4.x * v4.x + v4.y * v4.y + v4.z * v4.z + v4.w * v4.w;
    const int* nb_ = n + (size_t)b * K;
    for (int k = 0; k < K; ++k) {
      int nid = nb_[k];
      float4 n4 = *(const float4*)&Z[(size_t)nid * 64 + sl * 4];
      float d = u4.x * n4.x + u4.y * n4.y + u4.z * n4.z + u4.w * n4.w;
      regl += n4.x * n4.x + n4.y * n4.y + n4.z * n4.z + n4.w * n4.w;
#pragma unroll
      for (int off = 8; off; off >>= 1) d += __shfl_xor(d, off);
      if (sl == 0) xbuf[bloc][k] = sp - d;
    }
#pragma unroll
    for (int off = 8; off; off >>= 1) regl += __shfl_xor(regl, off);
    float sb = 0.f;
    for (int k = sl; k < K; k += 16) {
      float x = xbuf[bloc][k];
      sb += fminf(x, 0.f) - log1pf(expf(-fabsf(x)));
    }
#pragma unroll
    for (int off = 8; off; off >>= 1) sb += __shfl_xor(sb, off);
    lossb = -sb + 1e-4f * regl;
  }
  if (sl == 0) part[bloc] = (b < B) ? lossb : 0.f;
  __syncthreads();
  if (t == 0) {
    float s = 0.f;
#pragma unroll
    for (int i = 0; i < 16; ++i) s += part[i];
    unsafeAtomicAdd(out, s);
  }
}

extern "C" void kernel_launch(void* const* d_in, const int* in_sizes, int n_in,
                              void* d_out, int out_size, void* d_ws, size_t ws_size,
                              hipStream_t stream) {
  const float* E  = (const float*)d_in[0];
  const float* E2 = (const float*)d_in[1];
  const float* Wm = (const float*)d_in[2];
  const float* bm = (const float*)d_in[3];
  const float* AW = (const float*)d_in[4];
  const float* ab = (const float*)d_in[5];
  const float* qw = (const float*)d_in[6];
  const int*   ei = (const int*)d_in[7];
  const int*   u  = (const int*)d_in[8];
  const int*   v  = (const int*)d_in[9];
  const int*   nn = (const int*)d_in[10];
  const float* w  = (const float*)d_in[11];

  const int NN = in_sizes[0] / 64;        // 150000
  const int NE = in_sizes[7] / 2;         // 3200000
  const int B  = in_sizes[8];             // 16384
  const int K  = in_sizes[10] / B;        // 40

  const int* src = ei;
  const int* dst = ei + NE;

  // workspace layout
  float* ws     = (float*)d_ws;
  float* dinv   = ws;                         // NN floats
  float* b1     = dinv + NN;                  // NN*64
  float* b2     = b1 + (size_t)NN * 64;       // NN*64
  int*   deg_i  = (int*)(b2 + (size_t)NN * 64);   // NN ints
  int*   cursor = deg_i + NN;                 // NN ints
  int*   rowptr = cursor + NN;                // NN+1 ints
  int*   bsum   = rowptr + NN + 1;            // <=1024 ints
  int*   csrc   = bsum + 1024;                // NE ints
  float* cnorm  = (float*)(csrc + NE);        // NE floats
  float* outf   = (float*)d_out;

  const int nb = (NN + 255) / 256;            // scan blocks (<=1024)

  hipMemsetAsync(deg_i, 0, (size_t)2 * NN * sizeof(int), stream);
  hipMemsetAsync(outf, 0, sizeof(float), stream);

  k_count<<<(NE + 255) / 256, 256, 0, stream>>>(dst, deg_i, NE);
  k_scan1<<<nb, 256, 0, stream>>>(deg_i, bsum, NN);
  k_scan2<<<1, 1024, 0, stream>>>(bsum, nb);
  k_scan3<<<nb, 256, 0, stream>>>(deg_i, bsum, rowptr, NN);
  k_dinv<<<(NN + 255) / 256, 256, 0, stream>>>(deg_i, dinv, NN);
  k_scatter<<<(NE + 255) / 256, 256, 0, stream>>>(src, dst, dinv, rowptr, cursor,
                                                  csrc, cnorm, NE);

  int gatherBlocks = ((size_t)NN * 16 + 255) / 256;   // 16 lanes per node
  k_gather<<<gatherBlocks, 256, 0, stream>>>(E, rowptr, csrc, cnorm, b1, NN);
  k_gather<<<gatherBlocks, 256, 0, stream>>>(b1, rowptr, csrc, cnorm, b2, NN);

  int nodeTiles = (NN + 63) / 64;
  k_node<<<nodeTiles, 256, 0, stream>>>(E, E2, Wm, bm, AW, ab, qw, b1, b2, NN);

  k_score<<<(B + 15) / 16, 256, 0, stream>>>(b1, u, v, nn, w, outf, B, K);
}

// Round 6
// 750.823 us; speedup vs baseline: 3.4709x; 1.1045x over previous
//
#include <hip/hip_runtime.h>
#include <math.h>

// ---------------------------------------------------------------------------
// SiReN loss on MI355X — round 6: k_node occupancy fix.
// Single re-staged weight buffer (k-major, stride 66), shfl-based attention
// reduction (no red/alpha LDS), LDS 94.7 KB -> 50.5 KB => 3 blocks/CU.
// ---------------------------------------------------------------------------

__global__ void k_count(const int* __restrict__ dst, int* __restrict__ deg, int NE) {
  int e = blockIdx.x * blockDim.x + threadIdx.x;
  if (e < NE) atomicAdd(&deg[dst[e]], 1);
}

__global__ void k_scan1(const int* __restrict__ deg, int* __restrict__ bsum, int NN) {
  __shared__ int sm[256];
  int t = threadIdx.x;
  int i = blockIdx.x * 256 + t;
  sm[t] = (i < NN) ? deg[i] : 0;
  __syncthreads();
  for (int s = 128; s > 0; s >>= 1) {
    if (t < s) sm[t] += sm[t + s];
    __syncthreads();
  }
  if (t == 0) bsum[blockIdx.x] = sm[0];
}

__global__ void k_scan2(int* __restrict__ bsum, int nb) {
  __shared__ int sm[1024];
  int t = threadIdx.x;
  int v = (t < nb) ? bsum[t] : 0;
  sm[t] = v;
  __syncthreads();
  for (int off = 1; off < 1024; off <<= 1) {
    int add = (t >= off) ? sm[t - off] : 0;
    __syncthreads();
    sm[t] += add;
    __syncthreads();
  }
  if (t < nb) bsum[t] = sm[t] - v;  // exclusive
}

__global__ void k_scan3(const int* __restrict__ deg, const int* __restrict__ bsum,
                        int* __restrict__ rowptr, int NN) {
  __shared__ int sm[256];
  int t = threadIdx.x;
  int i = blockIdx.x * 256 + t;
  int v = (i < NN) ? deg[i] : 0;
  sm[t] = v;
  __syncthreads();
  for (int off = 1; off < 256; off <<= 1) {
    int add = (t >= off) ? sm[t - off] : 0;
    __syncthreads();
    sm[t] += add;
    __syncthreads();
  }
  int incl = sm[t] + bsum[blockIdx.x];
  if (i < NN) rowptr[i] = incl - v;
  if (i == NN - 1) rowptr[NN] = incl;
}

__global__ void k_dinv(const int* __restrict__ deg, float* __restrict__ dinv, int NN) {
  int i = blockIdx.x * blockDim.x + threadIdx.x;
  if (i < NN) {
    int d = deg[i];
    dinv[i] = (d > 0) ? rsqrtf((float)d) : 0.f;
  }
}

__global__ void k_scatter(const int* __restrict__ src, const int* __restrict__ dst,
                          const float* __restrict__ dinv, const int* __restrict__ rowptr,
                          int* __restrict__ cursor, int* __restrict__ csrc,
                          float* __restrict__ cnorm, int NE) {
  int e = blockIdx.x * blockDim.x + threadIdx.x;
  if (e >= NE) return;
  int s = src[e], d = dst[e];
  int pos = rowptr[d] + atomicAdd(&cursor[d], 1);
  csrc[pos] = s;
  cnorm[pos] = dinv[s] * dinv[d];
}

// 16-lane sub-group per node, lane = 4 dims (float4); 4 nodes per wave
__global__ __launch_bounds__(256) void k_gather(const float* __restrict__ x,
                                                const int* __restrict__ rowptr,
                                                const int* __restrict__ csrc,
                                                const float* __restrict__ cnorm,
                                                float* __restrict__ out, int NN) {
  int gid = blockIdx.x * blockDim.x + threadIdx.x;
  int node = gid >> 4;
  if (node >= NN) return;
  int sl = gid & 15;
  int beg = rowptr[node], end = rowptr[node + 1];
  float ax = 0.f, ay = 0.f, az = 0.f, aw = 0.f;
  int i = beg;
  for (; i + 1 < end; i += 2) {
    int s0 = csrc[i], s1 = csrc[i + 1];
    float n0 = cnorm[i], n1 = cnorm[i + 1];
    float4 x0 = *(const float4*)&x[(size_t)s0 * 64 + sl * 4];
    float4 x1 = *(const float4*)&x[(size_t)s1 * 64 + sl * 4];
    ax += n0 * x0.x; ay += n0 * x0.y; az += n0 * x0.z; aw += n0 * x0.w;
    ax += n1 * x1.x; ay += n1 * x1.y; az += n1 * x1.z; aw += n1 * x1.w;
  }
  if (i < end) {
    float n0 = cnorm[i];
    float4 x0 = *(const float4*)&x[(size_t)csrc[i] * 64 + sl * 4];
    ax += n0 * x0.x; ay += n0 * x0.y; az += n0 * x0.z; aw += n0 * x0.w;
  }
  float4 r; r.x = ax; r.y = ay; r.z = az; r.w = aw;
  *(float4*)&out[(size_t)node * 64 + sl * 4] = r;
}

// ---------------------------------------------------------------------------
// k_node v3: one 64-node tile per block; 4x4 register tiling; ONE weight
// buffer re-staged W0 -> W1 -> AW (k-major, stride 66); shfl reductions.
// LDS = Wl + TA + TB + biases ~= 50.5 KB -> 3 blocks/CU.
// ---------------------------------------------------------------------------
#define TS 66

__device__ inline float fast_tanh(float x) {
  float t = __expf(fminf(fmaxf(2.f * x, -30.f), 30.f));
  return (t - 1.f) / (t + 1.f);
}

__global__ __launch_bounds__(256, 4) void k_node(const float* __restrict__ E,
                                                 const float* __restrict__ E2,
                                                 const float* __restrict__ Wm,
                                                 const float* __restrict__ bm,
                                                 const float* __restrict__ AW,
                                                 const float* __restrict__ ab,
                                                 const float* __restrict__ qw,
                                                 float* __restrict__ b1buf,
                                                 const float* __restrict__ b2buf,
                                                 int NN) {
  __shared__ float Wl[64 * TS];     // current weight, k-major: Wl[k*TS + col]
  __shared__ float TA[64 * TS];     // E2 tile -> ZN tile (node-major)
  __shared__ float TB[64 * TS];     // H tile  -> ZP tile (node-major)
  __shared__ float b0s[64], b1s[64], abs_[64], qs[64];

  int tid = threadIdx.x;
  int tx = tid & 15, ty = tid >> 4;        // ty 0..15
  int lrow = tid >> 2;                     // staging row 0..63
  int lcol = (tid & 3) * 16;               // staging col base
  int node0 = blockIdx.x * 64;
  int snode = node0 + lrow;
  bool sok = snode < NN;

  // stage W0 (k-major) + E2 tile + biases
  for (int idx = tid; idx < 4096; idx += 256) {
    int j = idx >> 6, k = idx & 63;
    Wl[k * TS + j] = Wm[idx];
  }
  if (tid < 64) { b0s[tid] = bm[tid]; b1s[tid] = bm[64 + tid]; abs_[tid] = ab[tid]; qs[tid] = qw[tid]; }
  {
    const float4 z4 = make_float4(0.f, 0.f, 0.f, 0.f);
    const float* sp = E2 + (size_t)snode * 64 + lcol;
#pragma unroll
    for (int c = 0; c < 4; ++c) {
      float4 xv = sok ? *(const float4*)(sp + 4 * c) : z4;
      float2* wp = (float2*)&TA[lrow * TS + lcol + 4 * c];
      wp[0] = make_float2(xv.x, xv.y);
      wp[1] = make_float2(xv.z, xv.w);
    }
  }
  __syncthreads();

  // GEMM1: acc = E2 @ W0^T + b0
  float acc[4][4];
#pragma unroll
  for (int a = 0; a < 4; ++a)
#pragma unroll
    for (int b = 0; b < 4; ++b) acc[a][b] = b0s[tx + 16 * b];
#pragma unroll 4
  for (int k = 0; k < 64; ++k) {
    float xv[4], wv[4];
#pragma unroll
    for (int a = 0; a < 4; ++a) xv[a] = TA[(ty + 16 * a) * TS + k];
#pragma unroll
    for (int b = 0; b < 4; ++b) wv[b] = Wl[k * TS + tx + 16 * b];
#pragma unroll
    for (int a = 0; a < 4; ++a)
#pragma unroll
      for (int b = 0; b < 4; ++b) acc[a][b] += xv[a] * wv[b];
  }
  __syncthreads();   // Wl (W0) reads done

  // re-stage Wl = W1; write H = relu(acc) into TB
  for (int idx = tid; idx < 4096; idx += 256) {
    int j = idx >> 6, k = idx & 63;
    Wl[k * TS + j] = Wm[4096 + idx];
  }
#pragma unroll
  for (int a = 0; a < 4; ++a)
#pragma unroll
    for (int b = 0; b < 4; ++b)
      TB[(ty + 16 * a) * TS + tx + 16 * b] = fmaxf(acc[a][b], 0.f);
  __syncthreads();

  // GEMM2: acc = H @ W1^T + b1
#pragma unroll
  for (int a = 0; a < 4; ++a)
#pragma unroll
    for (int b = 0; b < 4; ++b) acc[a][b] = b1s[tx + 16 * b];
#pragma unroll 4
  for (int k = 0; k < 64; ++k) {
    float xv[4], wv[4];
#pragma unroll
    for (int a = 0; a < 4; ++a) xv[a] = TB[(ty + 16 * a) * TS + k];
#pragma unroll
    for (int b = 0; b < 4; ++b) wv[b] = Wl[k * TS + tx + 16 * b];
#pragma unroll
    for (int a = 0; a < 4; ++a)
#pragma unroll
      for (int b = 0; b < 4; ++b) acc[a][b] += xv[a] * wv[b];
  }
  __syncthreads();   // Wl (W1) + TB (H) reads done

  // re-stage Wl = AW; ZN = relu(acc) -> TA; ZP = (E+b1+b2)/3 -> TB
  for (int idx = tid; idx < 4096; idx += 256) {
    int j = idx >> 6, k = idx & 63;
    Wl[k * TS + j] = AW[idx];
  }
#pragma unroll
  for (int a = 0; a < 4; ++a)
#pragma unroll
    for (int b = 0; b < 4; ++b)
      TA[(ty + 16 * a) * TS + tx + 16 * b] = fmaxf(acc[a][b], 0.f);
  {
    const float4 z4 = make_float4(0.f, 0.f, 0.f, 0.f);
    const float* pe = E + (size_t)snode * 64 + lcol;
    const float* p1 = b1buf + (size_t)snode * 64 + lcol;
    const float* p2 = b2buf + (size_t)snode * 64 + lcol;
#pragma unroll
    for (int c = 0; c < 4; ++c) {
      float4 e4 = sok ? *(const float4*)(pe + 4 * c) : z4;
      float4 a4 = sok ? *(const float4*)(p1 + 4 * c) : z4;
      float4 c4 = sok ? *(const float4*)(p2 + 4 * c) : z4;
      float2* wp = (float2*)&TB[lrow * TS + lcol + 4 * c];
      wp[0] = make_float2((e4.x + a4.x + c4.x) * (1.f / 3.f),
                          (e4.y + a4.y + c4.y) * (1.f / 3.f));
      wp[1] = make_float2((e4.z + a4.z + c4.z) * (1.f / 3.f),
                          (e4.w + a4.w + c4.w) * (1.f / 3.f));
    }
  }
  __syncthreads();

  // Attention GEMMs: ac1 = ZP@AW^T+ab (TB), ac2 = ZN@AW^T+ab (TA)
  float ac1[4][4], ac2[4][4];
#pragma unroll
  for (int a = 0; a < 4; ++a)
#pragma unroll
    for (int b = 0; b < 4; ++b) { ac1[a][b] = abs_[tx + 16 * b]; ac2[a][b] = ac1[a][b]; }
#pragma unroll 4
  for (int k = 0; k < 64; ++k) {
    float zp[4], zn[4], wv[4];
#pragma unroll
    for (int a = 0; a < 4; ++a) {
      zp[a] = TB[(ty + 16 * a) * TS + k];
      zn[a] = TA[(ty + 16 * a) * TS + k];
    }
#pragma unroll
    for (int b = 0; b < 4; ++b) wv[b] = Wl[k * TS + tx + 16 * b];
#pragma unroll
    for (int a = 0; a < 4; ++a)
#pragma unroll
      for (int b = 0; b < 4; ++b) {
        ac1[a][b] += zp[a] * wv[b];
        ac2[a][b] += zn[a] * wv[b];
      }
  }

  // per-node q-dots of tanh + 16-lane shfl reduce (tx-lanes are consecutive)
  float a0v[4], a1v[4];
#pragma unroll
  for (int a = 0; a < 4; ++a) {
    float p1 = 0.f, p2 = 0.f;
#pragma unroll
    for (int b = 0; b < 4; ++b) {
      float q = qs[tx + 16 * b];
      p1 += fast_tanh(ac1[a][b]) * q;
      p2 += fast_tanh(ac2[a][b]) * q;
    }
#pragma unroll
    for (int off = 8; off; off >>= 1) {
      p1 += __shfl_xor(p1, off);
      p2 += __shfl_xor(p2, off);
    }
    float m = fmaxf(p1, p2);
    float e1 = __expf(p1 - m), e2 = __expf(p2 - m);
    float inv = 1.f / (e1 + e2);
    a0v[a] = e1 * inv;
    a1v[a] = e2 * inv;
  }

  // epilogue: Z = a0*ZP + a1*ZN directly to global
#pragma unroll
  for (int a = 0; a < 4; ++a) {
    int node = node0 + ty + 16 * a;
    if (node < NN) {
      float* op = b1buf + (size_t)node * 64;
#pragma unroll
      for (int b = 0; b < 4; ++b) {
        int col = tx + 16 * b;
        int base = (ty + 16 * a) * TS + col;
        op[col] = a0v[a] * TB[base] + a1v[a] * TA[base];
      }
    }
  }
}

// 16-lane sub-group per batch element; block handles 16; grid = ceil(B/16)
__global__ __launch_bounds__(256) void k_score(const float* __restrict__ Z,
                                               const int* __restrict__ u,
                                               const int* __restrict__ v,
                                               const int* __restrict__ n,
                                               const float* __restrict__ w,
                                               float* __restrict__ out, int B, int K) {
  __shared__ float xbuf[16][65];   // K <= 64
  __shared__ float part[16];
  int t = threadIdx.x;
  int wv = t >> 6, lane = t & 63;
  int sg = lane >> 4, sl = lane & 15;
  int bloc = wv * 4 + sg;
  int b = blockIdx.x * 16 + bloc;
  float lossb = 0.f;
  if (b < B) {
    int uid = u[b], vid = v[b];
    float4 u4 = *(const float4*)&Z[(size_t)uid * 64 + sl * 4];
    float4 v4 = *(const float4*)&Z[(size_t)vid * 64 + sl * 4];
    float p = u4.x * v4.x + u4.y * v4.y + u4.z * v4.z + u4.w * v4.w;
#pragma unroll
    for (int off = 8; off; off >>= 1) p += __shfl_xor(p, off);
    float wb = w[b];
    float sgn = (wb > 0.f) ? 1.f : ((wb < 0.f) ? -1.f : 0.f);
    float sp = sgn * p;
    float regl = u4.x * u4.x + u4.y * u4.y + u4.z * u4.z + u4.w * u4.w
               + v4.x * v4.x + v4.y * v4.y + v4.z * v4.z + v4.w * v4.w;
    const int* nb_ = n + (size_t)b * K;
    for (int k = 0; k < K; ++k) {
      int nid = nb_[k];
      float4 n4 = *(const float4*)&Z[(size_t)nid * 64 + sl * 4];
      float d = u4.x * n4.x + u4.y * n4.y + u4.z * n4.z + u4.w * n4.w;
      regl += n4.x * n4.x + n4.y * n4.y + n4.z * n4.z + n4.w * n4.w;
#pragma unroll
      for (int off = 8; off; off >>= 1) d += __shfl_xor(d, off);
      if (sl == 0) xbuf[bloc][k] = sp - d;
    }
#pragma unroll
    for (int off = 8; off; off >>= 1) regl += __shfl_xor(regl, off);
    float sb = 0.f;
    for (int k = sl; k < K; k += 16) {
      float x = xbuf[bloc][k];
      sb += fminf(x, 0.f) - log1pf(expf(-fabsf(x)));
    }
#pragma unroll
    for (int off = 8; off; off >>= 1) sb += __shfl_xor(sb, off);
    lossb = -sb + 1e-4f * regl;
  }
  if (sl == 0) part[bloc] = (b < B) ? lossb : 0.f;
  __syncthreads();
  if (t == 0) {
    float s = 0.f;
#pragma unroll
    for (int i = 0; i < 16; ++i) s += part[i];
    unsafeAtomicAdd(out, s);
  }
}

extern "C" void kernel_launch(void* const* d_in, const int* in_sizes, int n_in,
                              void* d_out, int out_size, void* d_ws, size_t ws_size,
                              hipStream_t stream) {
  const float* E  = (const float*)d_in[0];
  const float* E2 = (const float*)d_in[1];
  const float* Wm = (const float*)d_in[2];
  const float* bm = (const float*)d_in[3];
  const float* AW = (const float*)d_in[4];
  const float* ab = (const float*)d_in[5];
  const float* qw = (const float*)d_in[6];
  const int*   ei = (const int*)d_in[7];
  const int*   u  = (const int*)d_in[8];
  const int*   v  = (const int*)d_in[9];
  const int*   nn = (const int*)d_in[10];
  const float* w  = (const float*)d_in[11];

  const int NN = in_sizes[0] / 64;        // 150000
  const int NE = in_sizes[7] / 2;         // 3200000
  const int B  = in_sizes[8];             // 16384
  const int K  = in_sizes[10] / B;        // 40

  const int* src = ei;
  const int* dst = ei + NE;

  // workspace layout
  float* ws     = (float*)d_ws;
  float* dinv   = ws;                         // NN floats
  float* b1     = dinv + NN;                  // NN*64
  float* b2     = b1 + (size_t)NN * 64;       // NN*64
  int*   deg_i  = (int*)(b2 + (size_t)NN * 64);   // NN ints
  int*   cursor = deg_i + NN;                 // NN ints
  int*   rowptr = cursor + NN;                // NN+1 ints
  int*   bsum   = rowptr + NN + 1;            // <=1024 ints
  int*   csrc   = bsum + 1024;                // NE ints
  float* cnorm  = (float*)(csrc + NE);        // NE floats
  float* outf   = (float*)d_out;

  const int nb = (NN + 255) / 256;            // scan blocks (<=1024)

  hipMemsetAsync(deg_i, 0, (size_t)2 * NN * sizeof(int), stream);
  hipMemsetAsync(outf, 0, sizeof(float), stream);

  k_count<<<(NE + 255) / 256, 256, 0, stream>>>(dst, deg_i, NE);
  k_scan1<<<nb, 256, 0, stream>>>(deg_i, bsum, NN);
  k_scan2<<<1, 1024, 0, stream>>>(bsum, nb);
  k_scan3<<<nb, 256, 0, stream>>>(deg_i, bsum, rowptr, NN);
  k_dinv<<<(NN + 255) / 256, 256, 0, stream>>>(deg_i, dinv, NN);
  k_scatter<<<(NE + 255) / 256, 256, 0, stream>>>(src, dst, dinv, rowptr, cursor,
                                                  csrc, cnorm, NE);

  int gatherBlocks = ((size_t)NN * 16 + 255) / 256;   // 16 lanes per node
  k_gather<<<gatherBlocks, 256, 0, stream>>>(E, rowptr, csrc, cnorm, b1, NN);
  k_gather<<<gatherBlocks, 256, 0, stream>>>(b1, rowptr, csrc, cnorm, b2, NN);

  int nodeTiles = (NN + 63) / 64;
  k_node<<<nodeTiles, 256, 0, stream>>>(E, E2, Wm, bm, AW, ab, qw, b1, b2, NN);

  k_score<<<(B + 15) / 16, 256, 0, stream>>>(b1, u, v, nn, w, outf, B, K);
}